// Round 1
// baseline (319.432 us; speedup 1.0000x reference)
//
#include <hip/hip_runtime.h>
#include <hip/hip_bf16.h>

typedef __hip_bfloat16 bf16;
typedef float v4f __attribute__((ext_vector_type(4)));
typedef short v8s __attribute__((ext_vector_type(8)));

typedef const __attribute__((address_space(1))) void gvoid;
typedef __attribute__((address_space(3))) void lvoid;

__device__ __forceinline__ void async16(const void* g, void* l) {
  __builtin_amdgcn_global_load_lds((gvoid*)g, (lvoid*)l, 16, 0, 0);
}

// cardinal cubic B-spline on [0,4], 0 outside. Reference bspline(t) == b3(4t),
// wavelet(t) == b3(8t) - b3(8t-4). Clamp makes u>=4 exactly 0 (64-108+48-4).
__device__ __forceinline__ float b3(float u) {
  u = fminf(fmaxf(u, 0.f), 4.f);
  float t1 = fmaxf(u - 1.f, 0.f);
  float t2 = fmaxf(u - 2.f, 0.f);
  float t3 = fmaxf(u - 3.f, 0.f);
  float c0 = u * u * u;
  float c1 = t1 * t1 * t1;
  float c2 = t2 * t2 * t2;
  float c3 = t3 * t3 * t3;
  return (c0 - 4.f * c1 + 6.f * c2 - 4.f * c3) * (1.f / 6.f);
}

// m97-style NT GEMM mainloop: C[128 x NI*32] tile, BK=32, bf16 MFMA 16x16x32.
// A: [*, lda] row-major (M rows), B: [*, ldb] row-major (N rows, i.e. B^T).
template <int NI>
__device__ __forceinline__ void mfma_loop(const bf16* __restrict__ A,
                                          const bf16* __restrict__ B, int lda,
                                          int ldb, int kLen, bf16* As, bf16* Bs,
                                          v4f acc[4][NI]) {
  const int tid = threadIdx.x;
  const int wave = tid >> 6;
  const int lane = tid & 63;
  const int quad = lane >> 4;
  const int r16 = lane & 15;
  const int wm = (wave >> 1) * 64;
  const int wn = (wave & 1) * (NI * 16);
  char* AsC = (char*)As;
  char* BsC = (char*)Bs;
  const int f0 = tid, f1 = 256 + tid;
  const int r0 = f0 >> 2, c0 = (f0 & 3) << 3;
  const int r1 = f1 >> 2, c1 = (f1 & 3) << 3;
  for (int kk = 0; kk < kLen; kk += 32) {
    async16(A + (size_t)r0 * lda + kk + c0, AsC + wave * 1024);
    async16(A + (size_t)r1 * lda + kk + c1, AsC + 4096 + wave * 1024);
    async16(B + (size_t)r0 * ldb + kk + c0, BsC + wave * 1024);
    if (NI == 4)
      async16(B + (size_t)r1 * ldb + kk + c1, BsC + 4096 + wave * 1024);
    __syncthreads();
    v8s af[4], bfr[NI];
#pragma unroll
    for (int mi = 0; mi < 4; ++mi)
      af[mi] = *(const v8s*)(As + (wm + mi * 16 + r16) * 32 + quad * 8);
#pragma unroll
    for (int ni = 0; ni < NI; ++ni)
      bfr[ni] = *(const v8s*)(Bs + (wn + ni * 16 + r16) * 32 + quad * 8);
#pragma unroll
    for (int mi = 0; mi < 4; ++mi)
#pragma unroll
      for (int ni = 0; ni < NI; ++ni)
        acc[mi][ni] = __builtin_amdgcn_mfma_f32_16x16x32_bf16(
            af[mi], bfr[ni], acc[mi][ni], 0, 0, 0);
    __syncthreads();
  }
}

// per-row: sq-norm + bf16 cast of x into U[:, 0:256]
__global__ void prep(const float* __restrict__ x, bf16* __restrict__ U,
                     float* __restrict__ sq) {
  const int n = blockIdx.x, b = blockIdx.y, t = threadIdx.x;
  const size_t row = (size_t)b * 4096 + n;
  float v = x[row * 256 + t];
  U[row * 1280 + t] = __float2bfloat16(v);
  float s = v * v;
#pragma unroll
  for (int o = 32; o > 0; o >>= 1) s += __shfl_down(s, o, 64);
  __shared__ float ls[4];
  if ((t & 63) == 0) ls[t >> 6] = s;
  __syncthreads();
  if (t == 0) sq[row] = ls[0] + ls[1] + ls[2] + ls[3];
}

// fp32 [z][4096][256] -> bf16 [z][256][4096] (tiled transpose via LDS)
__global__ void transk(const float* __restrict__ src, bf16* __restrict__ dst) {
  __shared__ float tile[64][65];
  const int z = blockIdx.z;
  const float* s = src + (size_t)z * 4096 * 256;
  bf16* d = dst + (size_t)z * 256 * 4096;
  const int n0 = blockIdx.x * 64, d0 = blockIdx.y * 64;
  const int tx = threadIdx.x & 31, ty = threadIdx.x >> 5;
#pragma unroll
  for (int i = 0; i < 8; ++i) {
    const int r = ty + i * 8;
    const float2 v = *(const float2*)(s + (size_t)(n0 + r) * 256 + d0 + tx * 2);
    tile[r][tx * 2] = v.x;
    tile[r][tx * 2 + 1] = v.y;
  }
  __syncthreads();
#pragma unroll
  for (int i = 0; i < 8; ++i) {
    const int c = ty + i * 8;
    __hip_bfloat162 p;
    p.x = __float2bfloat16(tile[tx * 2][c]);
    p.y = __float2bfloat16(tile[tx * 2 + 1][c]);
    *(__hip_bfloat162*)(d + (size_t)(d0 + c) * 4096 + n0 + tx * 2) = p;
  }
}

// WbigT bf16 [128][1280]: rows k<256: W0[:,o]+Wlin[:,j]; 256..512: W1 (left);
// 512..768: W2 (left); 768..1024: W1 (right); 1024..1280: W2 (right)
__global__ void wbig(const float* __restrict__ Wk, const float* __restrict__ Wl,
                     bf16* __restrict__ WbT) {
  int idx = blockIdx.x * 256 + threadIdx.x;
  if (idx >= 128 * 1280) return;
  int j = idx / 1280, k = idx % 1280;
  int o = j & 63;
  float v = 0.f;
  if (k < 256)
    v = Wk[k * 64 + o] + Wl[k * 128 + j];
  else if (k < 512)
    v = (j < 64) ? Wk[16384 + (k - 256) * 64 + o] : 0.f;
  else if (k < 768)
    v = (j < 64) ? Wk[32768 + (k - 512) * 64 + o] : 0.f;
  else if (k < 1024)
    v = (j >= 64) ? Wk[16384 + (k - 768) * 64 + o] : 0.f;
  else
    v = (j >= 64) ? Wk[32768 + (k - 1024) * 64 + o] : 0.f;
  WbT[idx] = __float2bfloat16(v);
}

// S = x x^T tile + adjacency/spline epilogue -> bk, wk bf16 [4096][4096]
__global__ __launch_bounds__(256, 2) void gemm_s(const bf16* __restrict__ U,
                                                 const float* __restrict__ sq,
                                                 bf16* __restrict__ kmat) {
  __shared__ __align__(16) bf16 As[128 * 32];
  __shared__ __align__(16) bf16 Bs[128 * 32];
  const int z = blockIdx.z;
  const bf16* A = U + (size_t)z * 4096 * 1280 + (size_t)blockIdx.x * 128 * 1280;
  const bf16* B = U + (size_t)z * 4096 * 1280 + (size_t)blockIdx.y * 128 * 1280;
  v4f acc[4][4];
#pragma unroll
  for (int a = 0; a < 4; ++a)
#pragma unroll
    for (int b2 = 0; b2 < 4; ++b2) acc[a][b2] = (v4f){0.f, 0.f, 0.f, 0.f};
  mfma_loop<4>(A, B, 1280, 1280, 256, As, Bs, acc);
  const int tid = threadIdx.x, wave = tid >> 6, lane = tid & 63;
  const int quad = lane >> 4, r16 = lane & 15;
  const int wm = (wave >> 1) * 64, wn = (wave & 1) * 64;
  const float* sqr = sq + (size_t)z * 4096;
  bf16* bk = kmat + (size_t)(z * 2) * 4096 * 4096;
  bf16* wk = bk + (size_t)4096 * 4096;
  const int i0 = blockIdx.x * 128 + wm + quad * 4;
  const int j0 = blockIdx.y * 128 + wn + r16;
#pragma unroll
  for (int mi = 0; mi < 4; ++mi) {
#pragma unroll
    for (int r = 0; r < 4; ++r) {
      const int i = i0 + mi * 16 + r;
      const float si = sqr[i];
#pragma unroll
      for (int ni = 0; ni < 4; ++ni) {
        const int j = j0 + ni * 16;
        float s = acc[mi][ni][r];
        float d2 = fmaxf(si + sqr[j] - 2.f * s, 0.f);
        float t = __expf(d2 * (-1.f / 512.f));
        float bv = b3(4.f * t);
        float wv = b3(8.f * t) - b3(8.f * t - 4.f);
        size_t off = (size_t)i * 4096 + j;
        bk[off] = __float2bfloat16(bv);
        wk[off] = __float2bfloat16(wv);
      }
    }
  }
}

// h = K @ H : A = kernel matrix [4096][4096], Bt = H^T bf16 [256][4096]
// writes fp32 h (optional) and bf16 slice into U at uoffBase + kern*512
__global__ __launch_bounds__(256, 2) void gemm_h(
    const bf16* __restrict__ kmat, const bf16* __restrict__ BtBase,
    float* __restrict__ hout, bf16* __restrict__ U, int btShift, int uoffBase) {
  __shared__ __align__(16) bf16 As[128 * 32];
  __shared__ __align__(16) bf16 Bs[64 * 32];
  const int z = blockIdx.z;
  const bf16* A =
      kmat + (size_t)z * 4096 * 4096 + (size_t)blockIdx.x * 128 * 4096;
  const bf16* B = BtBase + (size_t)(z >> btShift) * 256 * 4096 +
                  (size_t)blockIdx.y * 64 * 4096;
  v4f acc[4][2];
#pragma unroll
  for (int a = 0; a < 4; ++a)
#pragma unroll
    for (int b2 = 0; b2 < 2; ++b2) acc[a][b2] = (v4f){0.f, 0.f, 0.f, 0.f};
  mfma_loop<2>(A, B, 4096, 4096, 4096, As, Bs, acc);
  const int tid = threadIdx.x, wave = tid >> 6, lane = tid & 63;
  const int quad = lane >> 4, r16 = lane & 15;
  const int wm = (wave >> 1) * 64, wn = (wave & 1) * 32;
  const int b = z >> 1, kern = z & 1;
  const int uoff = uoffBase + kern * 512;
  const int i0 = blockIdx.x * 128 + wm + quad * 4;
  const int j0 = blockIdx.y * 64 + wn + r16;
#pragma unroll
  for (int mi = 0; mi < 4; ++mi) {
#pragma unroll
    for (int r = 0; r < 4; ++r) {
      const int i = i0 + mi * 16 + r;
#pragma unroll
      for (int ni = 0; ni < 2; ++ni) {
        const int j = j0 + ni * 16;
        float v = acc[mi][ni][r];
        if (hout) hout[((size_t)z * 4096 + i) * 256 + j] = v;
        U[((size_t)(b * 4096 + i)) * 1280 + uoff + j] = __float2bfloat16(v);
      }
    }
  }
}

// out = relu(U @ Wbig + b_lin), M=8192, K=1280, N=128
__global__ __launch_bounds__(256, 2) void gemm_proj(
    const bf16* __restrict__ U, const bf16* __restrict__ WbT,
    const float* __restrict__ blin, float* __restrict__ out) {
  __shared__ __align__(16) bf16 As[128 * 32];
  __shared__ __align__(16) bf16 Bs[64 * 32];
  const bf16* A = U + (size_t)blockIdx.x * 128 * 1280;
  const bf16* B = WbT + (size_t)blockIdx.y * 64 * 1280;
  v4f acc[4][2];
#pragma unroll
  for (int a = 0; a < 4; ++a)
#pragma unroll
    for (int b2 = 0; b2 < 2; ++b2) acc[a][b2] = (v4f){0.f, 0.f, 0.f, 0.f};
  mfma_loop<2>(A, B, 1280, 1280, 1280, As, Bs, acc);
  const int tid = threadIdx.x, wave = tid >> 6, lane = tid & 63;
  const int quad = lane >> 4, r16 = lane & 15;
  const int wm = (wave >> 1) * 64, wn = (wave & 1) * 32;
  const int i0 = blockIdx.x * 128 + wm + quad * 4;
  const int j0 = blockIdx.y * 64 + wn + r16;
#pragma unroll
  for (int mi = 0; mi < 4; ++mi) {
#pragma unroll
    for (int r = 0; r < 4; ++r) {
      const int i = i0 + mi * 16 + r;
#pragma unroll
      for (int ni = 0; ni < 2; ++ni) {
        const int j = j0 + ni * 16;
        out[(size_t)i * 128 + j] = fmaxf(acc[mi][ni][r] + blin[j], 0.f);
      }
    }
  }
}

extern "C" void kernel_launch(void* const* d_in, const int* in_sizes, int n_in,
                              void* d_out, int out_size, void* d_ws,
                              size_t ws_size, hipStream_t stream) {
  const float* x = (const float*)d_in[0];
  const float* Wk = (const float*)d_in[1];
  const float* Wlin = (const float*)d_in[2];
  const float* blin = (const float*)d_in[3];
  float* out = (float*)d_out;
  char* w = (char*)d_ws;
  // workspace layout (bytes):
  bf16* kmat = (bf16*)(w);                  // 4 * 4096*4096 * 2 = 134217728
  float* h1 = (float*)(w + 134217728);      // 4 * 4096*256 * 4  = 16777216
  bf16* h1T = (bf16*)(w + 150994944);       // 4 * 256*4096 * 2  = 8388608
  bf16* xhT = (bf16*)(w + 159383552);       // 2 * 256*4096 * 2  = 4194304
  bf16* U = (bf16*)(w + 163577856);         // 8192*1280 * 2     = 20971520
  bf16* WbT = (bf16*)(w + 184549376);       // 128*1280 * 2      = 327680
  float* sqv = (float*)(w + 184877056);     // 8192 * 4          = 32768
  // total ~184.9 MB

  prep<<<dim3(4096, 2), 256, 0, stream>>>(x, U, sqv);
  transk<<<dim3(64, 4, 2), 256, 0, stream>>>(x, xhT);
  wbig<<<dim3(640), 256, 0, stream>>>(Wk, Wlin, WbT);
  gemm_s<<<dim3(32, 32, 2), 256, 0, stream>>>(U, sqv, kmat);
  gemm_h<<<dim3(32, 4, 4), 256, 0, stream>>>(kmat, xhT, h1, U, 1, 256);
  transk<<<dim3(64, 4, 4), 256, 0, stream>>>(h1, h1T);
  gemm_h<<<dim3(32, 4, 4), 256, 0, stream>>>(kmat, h1T, nullptr, U, 0, 512);
  gemm_proj<<<dim3(64, 2), 256, 0, stream>>>(U, WbT, blin, out);
}

// Round 2
// 273.984 us; speedup vs baseline: 1.1659x; 1.1659x over previous
//
#include <hip/hip_runtime.h>
#include <hip/hip_bf16.h>

typedef __hip_bfloat16 bf16;
typedef float v4f __attribute__((ext_vector_type(4)));
typedef short v8s __attribute__((ext_vector_type(8)));

typedef const __attribute__((address_space(1))) void gvoid;
typedef __attribute__((address_space(3))) void lvoid;

__device__ __forceinline__ void async16(const void* g, void* l) {
  __builtin_amdgcn_global_load_lds((gvoid*)g, (lvoid*)l, 16, 0, 0);
}

// cardinal cubic B-spline on [0,4], 0 outside. Reference bspline(t) == b3(4t),
// wavelet(t) == b3(8t) - b3(8t-4). Clamp makes u>=4 exactly 0 (64-108+48-4).
__device__ __forceinline__ float b3(float u) {
  u = fminf(fmaxf(u, 0.f), 4.f);
  float t1 = fmaxf(u - 1.f, 0.f);
  float t2 = fmaxf(u - 2.f, 0.f);
  float t3 = fmaxf(u - 3.f, 0.f);
  float c0 = u * u * u;
  float c1 = t1 * t1 * t1;
  float c2 = t2 * t2 * t2;
  float c3 = t3 * t3 * t3;
  return (c0 - 4.f * c1 + 6.f * c2 - 4.f * c3) * (1.f / 6.f);
}

// m97-style NT GEMM mainloop: C[128 x NI*32] tile, BK elems per stage,
// bf16 MFMA 16x16x32. A: [*, lda] row-major (M rows), B: [*, ldb] row-major
// (N rows, i.e. B^T). As: 128*BK bf16, Bs: NI*32*BK bf16.
template <int NI, int BK>
__device__ __forceinline__ void mfma_loop(const bf16* __restrict__ A,
                                          const bf16* __restrict__ B, int lda,
                                          int ldb, int kLen, bf16* As, bf16* Bs,
                                          v4f acc[4][NI]) {
  const int tid = threadIdx.x;
  const int wave = tid >> 6;
  const int lane = tid & 63;
  const int quad = lane >> 4;
  const int r16 = lane & 15;
  const int wm = (wave >> 1) * 64;
  const int wn = (wave & 1) * (NI * 16);
  constexpr int CPR = BK / 8;        // 16B chunks per row
  constexpr int AQ = 128 * CPR / 256;  // async groups for A
  constexpr int BQ = NI * 32 * CPR / 256;
  char* AsC = (char*)As;
  char* BsC = (char*)Bs;
  for (int kk = 0; kk < kLen; kk += BK) {
#pragma unroll
    for (int q = 0; q < AQ; ++q) {
      const int ch = tid + 256 * q;
      const int r = ch / CPR, c = (ch % CPR) * 8;
      async16(A + (size_t)r * lda + kk + c, AsC + q * 4096 + wave * 1024);
    }
#pragma unroll
    for (int q = 0; q < BQ; ++q) {
      const int ch = tid + 256 * q;
      const int r = ch / CPR, c = (ch % CPR) * 8;
      async16(B + (size_t)r * ldb + kk + c, BsC + q * 4096 + wave * 1024);
    }
    __syncthreads();
#pragma unroll
    for (int ks = 0; ks < BK / 32; ++ks) {
      v8s af[4], bfr[NI];
#pragma unroll
      for (int mi = 0; mi < 4; ++mi)
        af[mi] =
            *(const v8s*)(As + (wm + mi * 16 + r16) * BK + ks * 32 + quad * 8);
#pragma unroll
      for (int ni = 0; ni < NI; ++ni)
        bfr[ni] =
            *(const v8s*)(Bs + (wn + ni * 16 + r16) * BK + ks * 32 + quad * 8);
#pragma unroll
      for (int mi = 0; mi < 4; ++mi)
#pragma unroll
        for (int ni = 0; ni < NI; ++ni)
          acc[mi][ni] = __builtin_amdgcn_mfma_f32_16x16x32_bf16(
              af[mi], bfr[ni], acc[mi][ni], 0, 0, 0);
    }
    __syncthreads();
  }
}

// per-row: sq-norm + bf16 cast of x into U[:, 0:256]
__global__ void prep(const float* __restrict__ x, bf16* __restrict__ U,
                     float* __restrict__ sq) {
  const int n = blockIdx.x, b = blockIdx.y, t = threadIdx.x;
  const size_t row = (size_t)b * 4096 + n;
  float v = x[row * 256 + t];
  U[row * 1280 + t] = __float2bfloat16(v);
  float s = v * v;
#pragma unroll
  for (int o = 32; o > 0; o >>= 1) s += __shfl_down(s, o, 64);
  __shared__ float ls[4];
  if ((t & 63) == 0) ls[t >> 6] = s;
  __syncthreads();
  if (t == 0) sq[row] = ls[0] + ls[1] + ls[2] + ls[3];
}

// fp32 [z][4096][256] -> bf16 [z][256][4096] (tiled transpose via LDS)
__global__ void transk(const float* __restrict__ src, bf16* __restrict__ dst) {
  __shared__ float tile[64][65];
  const int z = blockIdx.z;
  const float* s = src + (size_t)z * 4096 * 256;
  bf16* d = dst + (size_t)z * 256 * 4096;
  const int n0 = blockIdx.x * 64, d0 = blockIdx.y * 64;
  const int tx = threadIdx.x & 31, ty = threadIdx.x >> 5;
#pragma unroll
  for (int i = 0; i < 8; ++i) {
    const int r = ty + i * 8;
    const float2 v = *(const float2*)(s + (size_t)(n0 + r) * 256 + d0 + tx * 2);
    tile[r][tx * 2] = v.x;
    tile[r][tx * 2 + 1] = v.y;
  }
  __syncthreads();
#pragma unroll
  for (int i = 0; i < 8; ++i) {
    const int c = ty + i * 8;
    __hip_bfloat162 p;
    p.x = __float2bfloat16(tile[tx * 2][c]);
    p.y = __float2bfloat16(tile[tx * 2 + 1][c]);
    *(__hip_bfloat162*)(d + (size_t)(d0 + c) * 4096 + n0 + tx * 2) = p;
  }
}

// WbigT bf16 [128][1280]
__global__ void wbig(const float* __restrict__ Wk, const float* __restrict__ Wl,
                     bf16* __restrict__ WbT) {
  int idx = blockIdx.x * 256 + threadIdx.x;
  if (idx >= 128 * 1280) return;
  int j = idx / 1280, k = idx % 1280;
  int o = j & 63;
  float v = 0.f;
  if (k < 256)
    v = Wk[k * 64 + o] + Wl[k * 128 + j];
  else if (k < 512)
    v = (j < 64) ? Wk[16384 + (k - 256) * 64 + o] : 0.f;
  else if (k < 768)
    v = (j < 64) ? Wk[32768 + (k - 512) * 64 + o] : 0.f;
  else if (k < 1024)
    v = (j >= 64) ? Wk[16384 + (k - 768) * 64 + o] : 0.f;
  else
    v = (j >= 64) ? Wk[32768 + (k - 1024) * 64 + o] : 0.f;
  WbT[idx] = __float2bfloat16(v);
}

// S = x x^T tile + adjacency/spline epilogue -> bk, wk bf16 [4096][4096]
__global__ __launch_bounds__(256, 2) void gemm_s(const bf16* __restrict__ U,
                                                 const float* __restrict__ sq,
                                                 bf16* __restrict__ kmat) {
  __shared__ __align__(16) bf16 As[128 * 32];
  __shared__ __align__(16) bf16 Bs[128 * 32];
  const int z = blockIdx.z;
  const bf16* A = U + (size_t)z * 4096 * 1280 + (size_t)blockIdx.x * 128 * 1280;
  const bf16* B = U + (size_t)z * 4096 * 1280 + (size_t)blockIdx.y * 128 * 1280;
  v4f acc[4][4];
#pragma unroll
  for (int a = 0; a < 4; ++a)
#pragma unroll
    for (int b2 = 0; b2 < 4; ++b2) acc[a][b2] = (v4f){0.f, 0.f, 0.f, 0.f};
  mfma_loop<4, 32>(A, B, 1280, 1280, 256, As, Bs, acc);
  const int tid = threadIdx.x, wave = tid >> 6, lane = tid & 63;
  const int quad = lane >> 4, r16 = lane & 15;
  const int wm = (wave >> 1) * 64, wn = (wave & 1) * 64;
  const float* sqr = sq + (size_t)z * 4096;
  bf16* bk = kmat + (size_t)(z * 2) * 4096 * 4096;
  bf16* wk = bk + (size_t)4096 * 4096;
  const int i0 = blockIdx.x * 128 + wm + quad * 4;
  const int j0 = blockIdx.y * 128 + wn + r16;
#pragma unroll
  for (int mi = 0; mi < 4; ++mi) {
#pragma unroll
    for (int r = 0; r < 4; ++r) {
      const int i = i0 + mi * 16 + r;
      const float si = sqr[i];
#pragma unroll
      for (int ni = 0; ni < 4; ++ni) {
        const int j = j0 + ni * 16;
        float s = acc[mi][ni][r];
        float d2 = fmaxf(si + sqr[j] - 2.f * s, 0.f);
        float t = __expf(d2 * (-1.f / 512.f));
        float bv = b3(4.f * t);
        float wv = b3(8.f * t) - b3(8.f * t - 4.f);
        size_t off = (size_t)i * 4096 + j;
        bk[off] = __float2bfloat16(bv);
        wk[off] = __float2bfloat16(wv);
      }
    }
  }
}

// h-partial = K[:, split] @ H[split, :] : split-K x2, BK=64.
// A = kernel matrix [4096][4096] bf16, Bt = H^T bf16 [256][4096].
// writes fp32 partial to hpart[split][z][4096][256].
__global__ __launch_bounds__(256, 4) void gemm_h(const bf16* __restrict__ kmat,
                                                 const bf16* __restrict__ BtBase,
                                                 float* __restrict__ hpart,
                                                 int btShift) {
  __shared__ __align__(16) bf16 As[128 * 64];
  __shared__ __align__(16) bf16 Bs[64 * 64];
  const int bz = blockIdx.z;
  const int z = bz >> 1, split = bz & 1;
  const int kk0 = split * 2048;
  const bf16* A = kmat + (size_t)z * 4096 * 4096 +
                  (size_t)blockIdx.x * 128 * 4096 + kk0;
  const bf16* B = BtBase + (size_t)(z >> btShift) * 256 * 4096 +
                  (size_t)blockIdx.y * 64 * 4096 + kk0;
  v4f acc[4][2];
#pragma unroll
  for (int a = 0; a < 4; ++a)
#pragma unroll
    for (int b2 = 0; b2 < 2; ++b2) acc[a][b2] = (v4f){0.f, 0.f, 0.f, 0.f};
  mfma_loop<2, 64>(A, B, 4096, 4096, 2048, As, Bs, acc);
  const int tid = threadIdx.x, wave = tid >> 6, lane = tid & 63;
  const int quad = lane >> 4, r16 = lane & 15;
  const int wm = (wave >> 1) * 64, wn = (wave & 1) * 32;
  float* H = hpart + ((size_t)split * 4 + z) * 4096 * 256;
  const int i0 = blockIdx.x * 128 + wm + quad * 4;
  const int j0 = blockIdx.y * 64 + wn + r16;
#pragma unroll
  for (int mi = 0; mi < 4; ++mi)
#pragma unroll
    for (int r = 0; r < 4; ++r) {
      const int i = i0 + mi * 16 + r;
#pragma unroll
      for (int ni = 0; ni < 2; ++ni)
        H[(size_t)i * 256 + j0 + ni * 16] = acc[mi][ni][r];
    }
}

// sum the two split-K partials; write bf16 slice into U[:, uoff..] and
// (pass 1 only) transposed bf16 into hT [z][256][4096].
__global__ void reduceT(const float* __restrict__ hpart, bf16* __restrict__ U,
                        bf16* __restrict__ hT, int uoffBase) {
  __shared__ float tile[64][65];
  const int z = blockIdx.z;
  const int b = z >> 1, kern = z & 1;
  const int uoff = uoffBase + kern * 512;
  const int n0 = blockIdx.x * 64, d0 = blockIdx.y * 64;
  const int tx = threadIdx.x & 31, ty = threadIdx.x >> 5;
  const float* s0 = hpart + (size_t)z * 4096 * 256;
  const float* s1 = s0 + (size_t)4 * 4096 * 256;
#pragma unroll
  for (int i = 0; i < 8; ++i) {
    const int r = ty + i * 8;
    const size_t off = (size_t)(n0 + r) * 256 + d0 + tx * 2;
    const float2 a = *(const float2*)(s0 + off);
    const float2 c = *(const float2*)(s1 + off);
    const float vx = a.x + c.x, vy = a.y + c.y;
    tile[r][tx * 2] = vx;
    tile[r][tx * 2 + 1] = vy;
    __hip_bfloat162 p;
    p.x = __float2bfloat16(vx);
    p.y = __float2bfloat16(vy);
    *(__hip_bfloat162*)(U + (size_t)(b * 4096 + n0 + r) * 1280 + uoff + d0 +
                        tx * 2) = p;
  }
  if (hT) {
    __syncthreads();
#pragma unroll
    for (int i = 0; i < 8; ++i) {
      const int c = ty + i * 8;
      __hip_bfloat162 p;
      p.x = __float2bfloat16(tile[tx * 2][c]);
      p.y = __float2bfloat16(tile[tx * 2 + 1][c]);
      *(__hip_bfloat162*)(hT + (size_t)z * 256 * 4096 + (size_t)(d0 + c) * 4096 +
                          n0 + tx * 2) = p;
    }
  }
}

// out = relu(U @ Wbig + b_lin), M=8192, K=1280, N=128
__global__ __launch_bounds__(256, 4) void gemm_proj(
    const bf16* __restrict__ U, const bf16* __restrict__ WbT,
    const float* __restrict__ blin, float* __restrict__ out) {
  __shared__ __align__(16) bf16 As[128 * 64];
  __shared__ __align__(16) bf16 Bs[64 * 64];
  const bf16* A = U + (size_t)blockIdx.x * 128 * 1280;
  const bf16* B = WbT + (size_t)blockIdx.y * 64 * 1280;
  v4f acc[4][2];
#pragma unroll
  for (int a = 0; a < 4; ++a)
#pragma unroll
    for (int b2 = 0; b2 < 2; ++b2) acc[a][b2] = (v4f){0.f, 0.f, 0.f, 0.f};
  mfma_loop<2, 64>(A, B, 1280, 1280, 1280, As, Bs, acc);
  const int tid = threadIdx.x, wave = tid >> 6, lane = tid & 63;
  const int quad = lane >> 4, r16 = lane & 15;
  const int wm = (wave >> 1) * 64, wn = (wave & 1) * 32;
  const int i0 = blockIdx.x * 128 + wm + quad * 4;
  const int j0 = blockIdx.y * 64 + wn + r16;
#pragma unroll
  for (int mi = 0; mi < 4; ++mi)
#pragma unroll
    for (int r = 0; r < 4; ++r) {
      const int i = i0 + mi * 16 + r;
#pragma unroll
      for (int ni = 0; ni < 2; ++ni) {
        const int j = j0 + ni * 16;
        out[(size_t)i * 128 + j] = fmaxf(acc[mi][ni][r] + blin[j], 0.f);
      }
    }
}

extern "C" void kernel_launch(void* const* d_in, const int* in_sizes, int n_in,
                              void* d_out, int out_size, void* d_ws,
                              size_t ws_size, hipStream_t stream) {
  const float* x = (const float*)d_in[0];
  const float* Wk = (const float*)d_in[1];
  const float* Wlin = (const float*)d_in[2];
  const float* blin = (const float*)d_in[3];
  float* out = (float*)d_out;
  char* w = (char*)d_ws;
  // workspace layout (bytes):
  bf16* kmat = (bf16*)(w);               // 4 * 4096*4096 * 2 = 134217728
  float* hpart = (float*)(w + 134217728);  // 2 * 4*4096*256*4 = 33554432
  bf16* h1T = (bf16*)(w + 167772160);    // 4 * 256*4096 * 2  = 8388608
  bf16* xhT = (bf16*)(w + 176160768);    // 2 * 256*4096 * 2  = 4194304
  bf16* U = (bf16*)(w + 180355072);      // 8192*1280 * 2     = 20971520
  bf16* WbT = (bf16*)(w + 201326592);    // 128*1280 * 2      = 327680
  float* sqv = (float*)(w + 201654272);  // 8192 * 4          = 32768
  // total ~201.7 MB

  prep<<<dim3(4096, 2), 256, 0, stream>>>(x, U, sqv);
  transk<<<dim3(64, 4, 2), 256, 0, stream>>>(x, xhT);
  wbig<<<dim3(640), 256, 0, stream>>>(Wk, Wlin, WbT);
  gemm_s<<<dim3(32, 32, 2), 256, 0, stream>>>(U, sqv, kmat);
  // pass 1: h1 = K @ x
  gemm_h<<<dim3(32, 4, 8), 256, 0, stream>>>(kmat, xhT, hpart, 1);
  reduceT<<<dim3(64, 4, 4), 256, 0, stream>>>(hpart, U, h1T, 256);
  // pass 2: h2 = K @ h1
  gemm_h<<<dim3(32, 4, 8), 256, 0, stream>>>(kmat, h1T, hpart, 0);
  reduceT<<<dim3(64, 4, 4), 256, 0, stream>>>(hpart, U, nullptr, 512);
  gemm_proj<<<dim3(64, 2), 256, 0, stream>>>(U, WbT, blin, out);
}

// Round 4
// 259.608 us; speedup vs baseline: 1.2304x; 1.0554x over previous
//
#include <hip/hip_runtime.h>
#include <hip/hip_bf16.h>

typedef __hip_bfloat16 bf16;
typedef float v4f __attribute__((ext_vector_type(4)));
typedef short v8s __attribute__((ext_vector_type(8)));

typedef const __attribute__((address_space(1))) void gvoid;
typedef __attribute__((address_space(3))) void lvoid;

__device__ __forceinline__ void async16(const void* g, void* l) {
  __builtin_amdgcn_global_load_lds((gvoid*)g, (lvoid*)l, 16, 0, 0);
}

// cardinal cubic B-spline on [0,4], 0 outside. Reference bspline(t) == b3(4t),
// wavelet(t) == b3(8t) - b3(8t-4). Clamp makes u>=4 exactly 0 (64-108+48-4).
__device__ __forceinline__ float b3(float u) {
  u = fminf(fmaxf(u, 0.f), 4.f);
  float t1 = fmaxf(u - 1.f, 0.f);
  float t2 = fmaxf(u - 2.f, 0.f);
  float t3 = fmaxf(u - 3.f, 0.f);
  float c0 = u * u * u;
  float c1 = t1 * t1 * t1;
  float c2 = t2 * t2 * t2;
  float c3 = t3 * t3 * t3;
  return (c0 - 4.f * c1 + 6.f * c2 - 4.f * c3) * (1.f / 6.f);
}

// m97-style NT GEMM mainloop: C[128 x NI*32] tile, BK elems per stage,
// bf16 MFMA 16x16x32. A: [*, lda] row-major (M rows), B: [*, ldb] row-major
// (N rows, i.e. B^T). As: 128*BK bf16, Bs: NI*32*BK bf16.
template <int NI, int BK>
__device__ __forceinline__ void mfma_loop(const bf16* __restrict__ A,
                                          const bf16* __restrict__ B, int lda,
                                          int ldb, int kLen, bf16* As, bf16* Bs,
                                          v4f acc[4][NI]) {
  const int tid = threadIdx.x;
  const int wave = tid >> 6;
  const int lane = tid & 63;
  const int quad = lane >> 4;
  const int r16 = lane & 15;
  const int wm = (wave >> 1) * 64;
  const int wn = (wave & 1) * (NI * 16);
  constexpr int CPR = BK / 8;          // 16B chunks per row
  constexpr int AQ = 128 * CPR / 256;  // async groups for A
  constexpr int BQ = NI * 32 * CPR / 256;
  char* AsC = (char*)As;
  char* BsC = (char*)Bs;
  for (int kk = 0; kk < kLen; kk += BK) {
#pragma unroll
    for (int q = 0; q < AQ; ++q) {
      const int ch = tid + 256 * q;
      const int r = ch / CPR, c = (ch % CPR) * 8;
      async16(A + (size_t)r * lda + kk + c, AsC + q * 4096 + wave * 1024);
    }
#pragma unroll
    for (int q = 0; q < BQ; ++q) {
      const int ch = tid + 256 * q;
      const int r = ch / CPR, c = (ch % CPR) * 8;
      async16(B + (size_t)r * ldb + kk + c, BsC + q * 4096 + wave * 1024);
    }
    __syncthreads();
#pragma unroll
    for (int ks = 0; ks < BK / 32; ++ks) {
      v8s af[4], bfr[NI];
#pragma unroll
      for (int mi = 0; mi < 4; ++mi)
        af[mi] =
            *(const v8s*)(As + (wm + mi * 16 + r16) * BK + ks * 32 + quad * 8);
#pragma unroll
      for (int ni = 0; ni < NI; ++ni)
        bfr[ni] =
            *(const v8s*)(Bs + (wn + ni * 16 + r16) * BK + ks * 32 + quad * 8);
#pragma unroll
      for (int mi = 0; mi < 4; ++mi)
#pragma unroll
        for (int ni = 0; ni < NI; ++ni)
          acc[mi][ni] = __builtin_amdgcn_mfma_f32_16x16x32_bf16(
              af[mi], bfr[ni], acc[mi][ni], 0, 0, 0);
    }
    __syncthreads();
  }
}

// per-row: sq-norm + bf16 cast of x into U[:, 0:256]
__global__ void prep(const float* __restrict__ x, bf16* __restrict__ U,
                     float* __restrict__ sq) {
  const int n = blockIdx.x, b = blockIdx.y, t = threadIdx.x;
  const size_t row = (size_t)b * 4096 + n;
  float v = x[row * 256 + t];
  U[row * 1280 + t] = __float2bfloat16(v);
  float s = v * v;
#pragma unroll
  for (int o = 32; o > 0; o >>= 1) s += __shfl_down(s, o, 64);
  __shared__ float ls[4];
  if ((t & 63) == 0) ls[t >> 6] = s;
  __syncthreads();
  if (t == 0) sq[row] = ls[0] + ls[1] + ls[2] + ls[3];
}

// fp32 [z][4096][256] -> bf16 [z][256][4096] (tiled transpose via LDS)
__global__ void transk(const float* __restrict__ src, bf16* __restrict__ dst) {
  __shared__ float tile[64][65];
  const int z = blockIdx.z;
  const float* s = src + (size_t)z * 4096 * 256;
  bf16* d = dst + (size_t)z * 256 * 4096;
  const int n0 = blockIdx.x * 64, d0 = blockIdx.y * 64;
  const int tx = threadIdx.x & 31, ty = threadIdx.x >> 5;
#pragma unroll
  for (int i = 0; i < 8; ++i) {
    const int r = ty + i * 8;
    const float2 v = *(const float2*)(s + (size_t)(n0 + r) * 256 + d0 + tx * 2);
    tile[r][tx * 2] = v.x;
    tile[r][tx * 2 + 1] = v.y;
  }
  __syncthreads();
#pragma unroll
  for (int i = 0; i < 8; ++i) {
    const int c = ty + i * 8;
    __hip_bfloat162 p;
    p.x = __float2bfloat16(tile[tx * 2][c]);
    p.y = __float2bfloat16(tile[tx * 2 + 1][c]);
    *(__hip_bfloat162*)(d + (size_t)(d0 + c) * 4096 + n0 + tx * 2) = p;
  }
}

// WbigT bf16 [128][1280]
__global__ void wbig(const float* __restrict__ Wk, const float* __restrict__ Wl,
                     bf16* __restrict__ WbT) {
  int idx = blockIdx.x * 256 + threadIdx.x;
  if (idx >= 128 * 1280) return;
  int j = idx / 1280, k = idx % 1280;
  int o = j & 63;
  float v = 0.f;
  if (k < 256)
    v = Wk[k * 64 + o] + Wl[k * 128 + j];
  else if (k < 512)
    v = (j < 64) ? Wk[16384 + (k - 256) * 64 + o] : 0.f;
  else if (k < 768)
    v = (j < 64) ? Wk[32768 + (k - 512) * 64 + o] : 0.f;
  else if (k < 1024)
    v = (j >= 64) ? Wk[16384 + (k - 768) * 64 + o] : 0.f;
  else
    v = (j >= 64) ? Wk[32768 + (k - 1024) * 64 + o] : 0.f;
  WbT[idx] = __float2bfloat16(v);
}

// S = x x^T tile + adjacency/spline epilogue -> bk, wk bf16 [4096][4096].
// Spline pair evaluated via a 4096-entry LDS LUT over t=exp(-d2/512) in (0,1]:
// lut[i] = packed (bf16 b3(4t), bf16 b3(8t)-b3(8t-4)) at t=(i+.5)/4096.
// Nearest-bin error ~5e-4 << bf16 quantization (2e-3) << 2% threshold.
__global__ __launch_bounds__(256, 2) void gemm_s(const bf16* __restrict__ U,
                                                 const float* __restrict__ sq,
                                                 bf16* __restrict__ kmat) {
  __shared__ __align__(16) bf16 As[128 * 64];
  __shared__ __align__(16) bf16 Bs[128 * 64];
  __shared__ unsigned lut[4096];
  const int tid = threadIdx.x;
  // build LUT (amortized: 16 entries/thread, barrier inside mfma_loop covers)
  for (int i = tid; i < 4096; i += 256) {
    float t = (i + 0.5f) * (1.f / 4096.f);
    float bv = b3(4.f * t);
    float wv = b3(8.f * t) - b3(8.f * t - 4.f);
    __hip_bfloat162 p;
    p.x = __float2bfloat16(bv);  // low 16 = b-kernel
    p.y = __float2bfloat16(wv);  // high 16 = wavelet
    lut[i] = *(unsigned*)&p;
  }
  const int z = blockIdx.z;
  const bf16* A = U + (size_t)z * 4096 * 1280 + (size_t)blockIdx.x * 128 * 1280;
  const bf16* B = U + (size_t)z * 4096 * 1280 + (size_t)blockIdx.y * 128 * 1280;
  v4f acc[4][4];
#pragma unroll
  for (int a = 0; a < 4; ++a)
#pragma unroll
    for (int b2 = 0; b2 < 4; ++b2) acc[a][b2] = (v4f){0.f, 0.f, 0.f, 0.f};
  mfma_loop<4, 64>(A, B, 1280, 1280, 256, As, Bs, acc);
  const int wave = tid >> 6, lane = tid & 63;
  const int quad = lane >> 4, r16 = lane & 15;
  const int wm = (wave >> 1) * 64, wn = (wave & 1) * 64;
  const float* sqr = sq + (size_t)z * 4096;
  unsigned short* bk = (unsigned short*)(kmat + (size_t)(z * 2) * 4096 * 4096);
  unsigned short* wk = bk + (size_t)4096 * 4096;
  const int i0 = blockIdx.x * 128 + wm + quad * 4;
  const int j0 = blockIdx.y * 128 + wn + r16;
  float sqj[4];
#pragma unroll
  for (int ni = 0; ni < 4; ++ni) sqj[ni] = sqr[j0 + ni * 16];
  const float c = -1.4426950408889634f / 512.f;  // -log2(e)/512
#pragma unroll
  for (int mi = 0; mi < 4; ++mi) {
#pragma unroll
    for (int r = 0; r < 4; ++r) {
      const int i = i0 + mi * 16 + r;
      const float si = sqr[i];
#pragma unroll
      for (int ni = 0; ni < 4; ++ni) {
        const int j = j0 + ni * 16;
        float s = acc[mi][ni][r];
        float d2 = fmaxf(si + sqj[ni] - 2.f * s, 0.f);
        float t = __builtin_amdgcn_exp2f(d2 * c);
        int idx = (int)fminf(t * 4096.f, 4095.f);
        unsigned pv = lut[idx];
        size_t off = (size_t)i * 4096 + j;
        bk[off] = (unsigned short)(pv & 0xffff);
        wk[off] = (unsigned short)(pv >> 16);
      }
    }
  }
}

// h-partial = K[:, split] @ H[split, :] : split-K x2, BK=64.
// A = kernel matrix [4096][4096] bf16, Bt = H^T bf16 [256][4096].
// writes fp32 partial to hpart[split][z][4096][256].
__global__ __launch_bounds__(256, 4) void gemm_h(const bf16* __restrict__ kmat,
                                                 const bf16* __restrict__ BtBase,
                                                 float* __restrict__ hpart,
                                                 int btShift) {
  __shared__ __align__(16) bf16 As[128 * 64];
  __shared__ __align__(16) bf16 Bs[64 * 64];
  const int bz = blockIdx.z;
  const int z = bz >> 1, split = bz & 1;
  const int kk0 = split * 2048;
  const bf16* A = kmat + (size_t)z * 4096 * 4096 +
                  (size_t)blockIdx.x * 128 * 4096 + kk0;
  const bf16* B = BtBase + (size_t)(z >> btShift) * 256 * 4096 +
                  (size_t)blockIdx.y * 64 * 4096 + kk0;
  v4f acc[4][2];
#pragma unroll
  for (int a = 0; a < 4; ++a)
#pragma unroll
    for (int b2 = 0; b2 < 2; ++b2) acc[a][b2] = (v4f){0.f, 0.f, 0.f, 0.f};
  mfma_loop<2, 64>(A, B, 4096, 4096, 2048, As, Bs, acc);
  const int tid = threadIdx.x, wave = tid >> 6, lane = tid & 63;
  const int quad = lane >> 4, r16 = lane & 15;
  const int wm = (wave >> 1) * 64, wn = (wave & 1) * 32;
  float* H = hpart + ((size_t)split * 4 + z) * 4096 * 256;
  const int i0 = blockIdx.x * 128 + wm + quad * 4;
  const int j0 = blockIdx.y * 64 + wn + r16;
#pragma unroll
  for (int mi = 0; mi < 4; ++mi)
#pragma unroll
    for (int r = 0; r < 4; ++r) {
      const int i = i0 + mi * 16 + r;
#pragma unroll
      for (int ni = 0; ni < 2; ++ni)
        H[(size_t)i * 256 + j0 + ni * 16] = acc[mi][ni][r];
    }
}

// sum the two split-K partials; write bf16 slice into U[:, uoff..] and
// (pass 1 only) transposed bf16 into hT [z][256][4096].
__global__ void reduceT(const float* __restrict__ hpart, bf16* __restrict__ U,
                        bf16* __restrict__ hT, int uoffBase) {
  __shared__ float tile[64][65];
  const int z = blockIdx.z;
  const int b = z >> 1, kern = z & 1;
  const int uoff = uoffBase + kern * 512;
  const int n0 = blockIdx.x * 64, d0 = blockIdx.y * 64;
  const int tx = threadIdx.x & 31, ty = threadIdx.x >> 5;
  const float* s0 = hpart + (size_t)z * 4096 * 256;
  const float* s1 = s0 + (size_t)4 * 4096 * 256;
#pragma unroll
  for (int i = 0; i < 8; ++i) {
    const int r = ty + i * 8;
    const size_t off = (size_t)(n0 + r) * 256 + d0 + tx * 2;
    const float2 a = *(const float2*)(s0 + off);
    const float2 c = *(const float2*)(s1 + off);
    const float vx = a.x + c.x, vy = a.y + c.y;
    tile[r][tx * 2] = vx;
    tile[r][tx * 2 + 1] = vy;
    __hip_bfloat162 p;
    p.x = __float2bfloat16(vx);
    p.y = __float2bfloat16(vy);
    *(__hip_bfloat162*)(U + (size_t)(b * 4096 + n0 + r) * 1280 + uoff + d0 +
                        tx * 2) = p;
  }
  if (hT) {
    __syncthreads();
#pragma unroll
    for (int i = 0; i < 8; ++i) {
      const int c = ty + i * 8;
      __hip_bfloat162 p;
      p.x = __float2bfloat16(tile[tx * 2][c]);
      p.y = __float2bfloat16(tile[tx * 2 + 1][c]);
      *(__hip_bfloat162*)(hT + (size_t)z * 256 * 4096 + (size_t)(d0 + c) * 4096 +
                          n0 + tx * 2) = p;
    }
  }
}

// out = relu(U @ Wbig + b_lin), M=8192, K=1280, N=128
__global__ __launch_bounds__(256, 4) void gemm_proj(
    const bf16* __restrict__ U, const bf16* __restrict__ WbT,
    const float* __restrict__ blin, float* __restrict__ out) {
  __shared__ __align__(16) bf16 As[128 * 64];
  __shared__ __align__(16) bf16 Bs[64 * 64];
  const bf16* A = U + (size_t)blockIdx.x * 128 * 1280;
  const bf16* B = WbT + (size_t)blockIdx.y * 64 * 1280;
  v4f acc[4][2];
#pragma unroll
  for (int a = 0; a < 4; ++a)
#pragma unroll
    for (int b2 = 0; b2 < 2; ++b2) acc[a][b2] = (v4f){0.f, 0.f, 0.f, 0.f};
  mfma_loop<2, 64>(A, B, 1280, 1280, 1280, As, Bs, acc);
  const int tid = threadIdx.x, wave = tid >> 6, lane = tid & 63;
  const int quad = lane >> 4, r16 = lane & 15;
  const int wm = (wave >> 1) * 64, wn = (wave & 1) * 32;
  const int i0 = blockIdx.x * 128 + wm + quad * 4;
  const int j0 = blockIdx.y * 64 + wn + r16;
#pragma unroll
  for (int mi = 0; mi < 4; ++mi)
#pragma unroll
    for (int r = 0; r < 4; ++r) {
      const int i = i0 + mi * 16 + r;
#pragma unroll
      for (int ni = 0; ni < 2; ++ni) {
        const int j = j0 + ni * 16;
        out[(size_t)i * 128 + j] = fmaxf(acc[mi][ni][r] + blin[j], 0.f);
      }
    }
}

extern "C" void kernel_launch(void* const* d_in, const int* in_sizes, int n_in,
                              void* d_out, int out_size, void* d_ws,
                              size_t ws_size, hipStream_t stream) {
  const float* x = (const float*)d_in[0];
  const float* Wk = (const float*)d_in[1];
  const float* Wlin = (const float*)d_in[2];
  const float* blin = (const float*)d_in[3];
  float* out = (float*)d_out;
  char* w = (char*)d_ws;
  // workspace layout (bytes):
  bf16* kmat = (bf16*)(w);                 // 4 * 4096*4096 * 2 = 134217728
  float* hpart = (float*)(w + 134217728);  // 2 * 4*4096*256*4  = 33554432
  bf16* h1T = (bf16*)(w + 167772160);      // 4 * 256*4096 * 2  = 8388608
  bf16* xhT = (bf16*)(w + 176160768);      // 2 * 256*4096 * 2  = 4194304
  bf16* U = (bf16*)(w + 180355072);        // 8192*1280 * 2     = 20971520
  bf16* WbT = (bf16*)(w + 201326592);      // 128*1280 * 2      = 327680
  float* sqv = (float*)(w + 201654272);    // 8192 * 4          = 32768
  // total ~201.7 MB

  prep<<<dim3(4096, 2), 256, 0, stream>>>(x, U, sqv);
  transk<<<dim3(64, 4, 2), 256, 0, stream>>>(x, xhT);
  wbig<<<dim3(640), 256, 0, stream>>>(Wk, Wlin, WbT);
  gemm_s<<<dim3(32, 32, 2), 256, 0, stream>>>(U, sqv, kmat);
  // pass 1: h1 = K @ x
  gemm_h<<<dim3(32, 4, 8), 256, 0, stream>>>(kmat, xhT, hpart, 1);
  reduceT<<<dim3(64, 4, 4), 256, 0, stream>>>(hpart, U, h1T, 256);
  // pass 2: h2 = K @ h1
  gemm_h<<<dim3(32, 4, 8), 256, 0, stream>>>(kmat, h1T, hpart, 0);
  reduceT<<<dim3(64, 4, 4), 256, 0, stream>>>(hpart, U, nullptr, 512);
  gemm_proj<<<dim3(64, 2), 256, 0, stream>>>(U, WbT, blin, out);
}

// Round 5
// 256.764 us; speedup vs baseline: 1.2441x; 1.0111x over previous
//
#include <hip/hip_runtime.h>
#include <hip/hip_bf16.h>

typedef __hip_bfloat16 bf16;
typedef float v4f __attribute__((ext_vector_type(4)));
typedef short v8s __attribute__((ext_vector_type(8)));

typedef const __attribute__((address_space(1))) void gvoid;
typedef __attribute__((address_space(3))) void lvoid;

__device__ __forceinline__ void async16(const void* g, void* l) {
  __builtin_amdgcn_global_load_lds((gvoid*)g, (lvoid*)l, 16, 0, 0);
}

// cardinal cubic B-spline on [0,4], 0 outside. Reference bspline(t) == b3(4t),
// wavelet(t) == b3(8t) - b3(8t-4). Clamp makes u>=4 exactly 0 (64-108+48-4).
__device__ __forceinline__ float b3(float u) {
  u = fminf(fmaxf(u, 0.f), 4.f);
  float t1 = fmaxf(u - 1.f, 0.f);
  float t2 = fmaxf(u - 2.f, 0.f);
  float t3 = fmaxf(u - 3.f, 0.f);
  float c0 = u * u * u;
  float c1 = t1 * t1 * t1;
  float c2 = t2 * t2 * t2;
  float c3 = t3 * t3 * t3;
  return (c0 - 4.f * c1 + 6.f * c2 - 4.f * c3) * (1.f / 6.f);
}

// m97-style NT GEMM mainloop: C[128 x NI*32] tile, BK elems per stage,
// bf16 MFMA 16x16x32. A: [*, lda] row-major (M rows), B: [*, ldb] row-major
// (N rows, i.e. B^T). As: 128*BK bf16, Bs: NI*32*BK bf16.
template <int NI, int BK>
__device__ __forceinline__ void mfma_loop(const bf16* __restrict__ A,
                                          const bf16* __restrict__ B, int lda,
                                          int ldb, int kLen, bf16* As, bf16* Bs,
                                          v4f acc[4][NI]) {
  const int tid = threadIdx.x;
  const int wave = tid >> 6;
  const int lane = tid & 63;
  const int quad = lane >> 4;
  const int r16 = lane & 15;
  const int wm = (wave >> 1) * 64;
  const int wn = (wave & 1) * (NI * 16);
  constexpr int CPR = BK / 8;          // 16B chunks per row
  constexpr int AQ = 128 * CPR / 256;  // async groups for A
  constexpr int BQ = NI * 32 * CPR / 256;
  char* AsC = (char*)As;
  char* BsC = (char*)Bs;
  for (int kk = 0; kk < kLen; kk += BK) {
#pragma unroll
    for (int q = 0; q < AQ; ++q) {
      const int ch = tid + 256 * q;
      const int r = ch / CPR, c = (ch % CPR) * 8;
      async16(A + (size_t)r * lda + kk + c, AsC + q * 4096 + wave * 1024);
    }
#pragma unroll
    for (int q = 0; q < BQ; ++q) {
      const int ch = tid + 256 * q;
      const int r = ch / CPR, c = (ch % CPR) * 8;
      async16(B + (size_t)r * ldb + kk + c, BsC + q * 4096 + wave * 1024);
    }
    __syncthreads();
#pragma unroll
    for (int ks = 0; ks < BK / 32; ++ks) {
      v8s af[4], bfr[NI];
#pragma unroll
      for (int mi = 0; mi < 4; ++mi)
        af[mi] =
            *(const v8s*)(As + (wm + mi * 16 + r16) * BK + ks * 32 + quad * 8);
#pragma unroll
      for (int ni = 0; ni < NI; ++ni)
        bfr[ni] =
            *(const v8s*)(Bs + (wn + ni * 16 + r16) * BK + ks * 32 + quad * 8);
#pragma unroll
      for (int mi = 0; mi < 4; ++mi)
#pragma unroll
        for (int ni = 0; ni < NI; ++ni)
          acc[mi][ni] = __builtin_amdgcn_mfma_f32_16x16x32_bf16(
              af[mi], bfr[ni], acc[mi][ni], 0, 0, 0);
    }
    __syncthreads();
  }
}

// per-row: sq-norm + bf16 cast of x into U[:, 0:256]
__global__ void prep(const float* __restrict__ x, bf16* __restrict__ U,
                     float* __restrict__ sq) {
  const int n = blockIdx.x, b = blockIdx.y, t = threadIdx.x;
  const size_t row = (size_t)b * 4096 + n;
  float v = x[row * 256 + t];
  U[row * 1280 + t] = __float2bfloat16(v);
  float s = v * v;
#pragma unroll
  for (int o = 32; o > 0; o >>= 1) s += __shfl_down(s, o, 64);
  __shared__ float ls[4];
  if ((t & 63) == 0) ls[t >> 6] = s;
  __syncthreads();
  if (t == 0) sq[row] = ls[0] + ls[1] + ls[2] + ls[3];
}

// fp32 [z][4096][256] -> bf16 [z][256][4096] (tiled transpose via LDS)
__global__ void transk(const float* __restrict__ src, bf16* __restrict__ dst) {
  __shared__ float tile[64][65];
  const int z = blockIdx.z;
  const float* s = src + (size_t)z * 4096 * 256;
  bf16* d = dst + (size_t)z * 256 * 4096;
  const int n0 = blockIdx.x * 64, d0 = blockIdx.y * 64;
  const int tx = threadIdx.x & 31, ty = threadIdx.x >> 5;
#pragma unroll
  for (int i = 0; i < 8; ++i) {
    const int r = ty + i * 8;
    const float2 v = *(const float2*)(s + (size_t)(n0 + r) * 256 + d0 + tx * 2);
    tile[r][tx * 2] = v.x;
    tile[r][tx * 2 + 1] = v.y;
  }
  __syncthreads();
#pragma unroll
  for (int i = 0; i < 8; ++i) {
    const int c = ty + i * 8;
    __hip_bfloat162 p;
    p.x = __float2bfloat16(tile[tx * 2][c]);
    p.y = __float2bfloat16(tile[tx * 2 + 1][c]);
    *(__hip_bfloat162*)(d + (size_t)(d0 + c) * 4096 + n0 + tx * 2) = p;
  }
}

// WbigT bf16 [128][1280]
__global__ void wbig(const float* __restrict__ Wk, const float* __restrict__ Wl,
                     bf16* __restrict__ WbT) {
  int idx = blockIdx.x * 256 + threadIdx.x;
  if (idx >= 128 * 1280) return;
  int j = idx / 1280, k = idx % 1280;
  int o = j & 63;
  float v = 0.f;
  if (k < 256)
    v = Wk[k * 64 + o] + Wl[k * 128 + j];
  else if (k < 512)
    v = (j < 64) ? Wk[16384 + (k - 256) * 64 + o] : 0.f;
  else if (k < 768)
    v = (j < 64) ? Wk[32768 + (k - 512) * 64 + o] : 0.f;
  else if (k < 1024)
    v = (j >= 64) ? Wk[16384 + (k - 768) * 64 + o] : 0.f;
  else
    v = (j >= 64) ? Wk[32768 + (k - 1024) * 64 + o] : 0.f;
  WbT[idx] = __float2bfloat16(v);
}

// S = x x^T tile + adjacency/spline epilogue -> bk, wk bf16 [4096][4096].
// Spline pair evaluated via a 4096-entry LDS LUT over t=exp(-d2/512) in (0,1]:
// lut[i] = packed (bf16 b3(4t), bf16 b3(8t)-b3(8t-4)) at t=(i+.5)/4096.
// Nearest-bin error ~5e-4 << bf16 quantization (2e-3) << 2% threshold.
__global__ __launch_bounds__(256, 2) void gemm_s(const bf16* __restrict__ U,
                                                 const float* __restrict__ sq,
                                                 bf16* __restrict__ kmat) {
  __shared__ __align__(16) bf16 As[128 * 64];
  __shared__ __align__(16) bf16 Bs[128 * 64];
  __shared__ unsigned lut[4096];
  const int tid = threadIdx.x;
  // build LUT (amortized: 16 entries/thread, barrier inside mfma_loop covers)
  for (int i = tid; i < 4096; i += 256) {
    float t = (i + 0.5f) * (1.f / 4096.f);
    float bv = b3(4.f * t);
    float wv = b3(8.f * t) - b3(8.f * t - 4.f);
    __hip_bfloat162 p;
    p.x = __float2bfloat16(bv);  // low 16 = b-kernel
    p.y = __float2bfloat16(wv);  // high 16 = wavelet
    lut[i] = *(unsigned*)&p;
  }
  const int z = blockIdx.z;
  const bf16* A = U + (size_t)z * 4096 * 1280 + (size_t)blockIdx.x * 128 * 1280;
  const bf16* B = U + (size_t)z * 4096 * 1280 + (size_t)blockIdx.y * 128 * 1280;
  v4f acc[4][4];
#pragma unroll
  for (int a = 0; a < 4; ++a)
#pragma unroll
    for (int b2 = 0; b2 < 4; ++b2) acc[a][b2] = (v4f){0.f, 0.f, 0.f, 0.f};
  mfma_loop<4, 64>(A, B, 1280, 1280, 256, As, Bs, acc);
  const int wave = tid >> 6, lane = tid & 63;
  const int quad = lane >> 4, r16 = lane & 15;
  const int wm = (wave >> 1) * 64, wn = (wave & 1) * 64;
  const float* sqr = sq + (size_t)z * 4096;
  unsigned short* bk = (unsigned short*)(kmat + (size_t)(z * 2) * 4096 * 4096);
  unsigned short* wk = bk + (size_t)4096 * 4096;
  const int i0 = blockIdx.x * 128 + wm + quad * 4;
  const int j0 = blockIdx.y * 128 + wn + r16;
  float sqj[4];
#pragma unroll
  for (int ni = 0; ni < 4; ++ni) sqj[ni] = sqr[j0 + ni * 16];
  const float c = -1.4426950408889634f / 512.f;  // -log2(e)/512
#pragma unroll
  for (int mi = 0; mi < 4; ++mi) {
#pragma unroll
    for (int r = 0; r < 4; ++r) {
      const int i = i0 + mi * 16 + r;
      const float si = sqr[i];
#pragma unroll
      for (int ni = 0; ni < 4; ++ni) {
        const int j = j0 + ni * 16;
        float s = acc[mi][ni][r];
        float d2 = fmaxf(si + sqj[ni] - 2.f * s, 0.f);
        float t = __builtin_amdgcn_exp2f(d2 * c);
        int idx = (int)fminf(t * 4096.f, 4095.f);
        unsigned pv = lut[idx];
        size_t off = (size_t)i * 4096 + j;
        bk[off] = (unsigned short)(pv & 0xffff);
        wk[off] = (unsigned short)(pv >> 16);
      }
    }
  }
}

// h-partial = K[:, split] @ H[split, :] : split-K x4, BK=64, 128x128 tile.
// A = kernel matrix [4096][4096] bf16, Bt = H^T bf16 [256][4096].
// writes fp32 partial to hpart[split][z][4096][256].
__global__ __launch_bounds__(256, 4) void gemm_h(const bf16* __restrict__ kmat,
                                                 const bf16* __restrict__ BtBase,
                                                 float* __restrict__ hpart,
                                                 int btShift) {
  __shared__ __align__(16) bf16 As[128 * 64];
  __shared__ __align__(16) bf16 Bs[128 * 64];
  const int bz = blockIdx.z;
  const int z = bz >> 2, split = bz & 3;
  const int kk0 = split * 1024;
  const bf16* A =
      kmat + (size_t)z * 4096 * 4096 + (size_t)blockIdx.x * 128 * 4096 + kk0;
  const bf16* B = BtBase + (size_t)(z >> btShift) * 256 * 4096 +
                  (size_t)blockIdx.y * 128 * 4096 + kk0;
  v4f acc[4][4];
#pragma unroll
  for (int a = 0; a < 4; ++a)
#pragma unroll
    for (int b2 = 0; b2 < 4; ++b2) acc[a][b2] = (v4f){0.f, 0.f, 0.f, 0.f};
  mfma_loop<4, 64>(A, B, 4096, 4096, 1024, As, Bs, acc);
  const int tid = threadIdx.x, wave = tid >> 6, lane = tid & 63;
  const int quad = lane >> 4, r16 = lane & 15;
  const int wm = (wave >> 1) * 64, wn = (wave & 1) * 64;
  float* H = hpart + ((size_t)split * 4 + z) * 4096 * 256;
  const int i0 = blockIdx.x * 128 + wm + quad * 4;
  const int j0 = blockIdx.y * 128 + wn + r16;
#pragma unroll
  for (int mi = 0; mi < 4; ++mi)
#pragma unroll
    for (int r = 0; r < 4; ++r) {
      const int i = i0 + mi * 16 + r;
#pragma unroll
      for (int ni = 0; ni < 4; ++ni)
        H[(size_t)i * 256 + j0 + ni * 16] = acc[mi][ni][r];
    }
}

// sum the four split-K partials; write bf16 slice into U[:, uoff..] and
// (pass 1 only) transposed bf16 into hT [z][256][4096].
__global__ void reduceT(const float* __restrict__ hpart, bf16* __restrict__ U,
                        bf16* __restrict__ hT, int uoffBase) {
  __shared__ float tile[64][65];
  const int z = blockIdx.z;
  const int b = z >> 1, kern = z & 1;
  const int uoff = uoffBase + kern * 512;
  const int n0 = blockIdx.x * 64, d0 = blockIdx.y * 64;
  const int tx = threadIdx.x & 31, ty = threadIdx.x >> 5;
  const size_t sstride = (size_t)4 * 4096 * 256;
  const float* s0 = hpart + (size_t)z * 4096 * 256;
#pragma unroll
  for (int i = 0; i < 8; ++i) {
    const int r = ty + i * 8;
    const size_t off = (size_t)(n0 + r) * 256 + d0 + tx * 2;
    float vx = 0.f, vy = 0.f;
#pragma unroll
    for (int k = 0; k < 4; ++k) {
      const float2 a = *(const float2*)(s0 + k * sstride + off);
      vx += a.x;
      vy += a.y;
    }
    tile[r][tx * 2] = vx;
    tile[r][tx * 2 + 1] = vy;
    __hip_bfloat162 p;
    p.x = __float2bfloat16(vx);
    p.y = __float2bfloat16(vy);
    *(__hip_bfloat162*)(U + (size_t)(b * 4096 + n0 + r) * 1280 + uoff + d0 +
                        tx * 2) = p;
  }
  if (hT) {
    __syncthreads();
#pragma unroll
    for (int i = 0; i < 8; ++i) {
      const int c = ty + i * 8;
      __hip_bfloat162 p;
      p.x = __float2bfloat16(tile[tx * 2][c]);
      p.y = __float2bfloat16(tile[tx * 2 + 1][c]);
      *(__hip_bfloat162*)(hT + (size_t)z * 256 * 4096 + (size_t)(d0 + c) * 4096 +
                          n0 + tx * 2) = p;
    }
  }
}

// out = relu(U @ Wbig + b_lin), M=8192, K=1280, N=128
__global__ __launch_bounds__(256, 4) void gemm_proj(
    const bf16* __restrict__ U, const bf16* __restrict__ WbT,
    const float* __restrict__ blin, float* __restrict__ out) {
  __shared__ __align__(16) bf16 As[128 * 64];
  __shared__ __align__(16) bf16 Bs[64 * 64];
  const bf16* A = U + (size_t)blockIdx.x * 128 * 1280;
  const bf16* B = WbT + (size_t)blockIdx.y * 64 * 1280;
  v4f acc[4][2];
#pragma unroll
  for (int a = 0; a < 4; ++a)
#pragma unroll
    for (int b2 = 0; b2 < 2; ++b2) acc[a][b2] = (v4f){0.f, 0.f, 0.f, 0.f};
  mfma_loop<2, 64>(A, B, 1280, 1280, 1280, As, Bs, acc);
  const int tid = threadIdx.x, wave = tid >> 6, lane = tid & 63;
  const int quad = lane >> 4, r16 = lane & 15;
  const int wm = (wave >> 1) * 64, wn = (wave & 1) * 32;
  const int i0 = blockIdx.x * 128 + wm + quad * 4;
  const int j0 = blockIdx.y * 64 + wn + r16;
#pragma unroll
  for (int mi = 0; mi < 4; ++mi)
#pragma unroll
    for (int r = 0; r < 4; ++r) {
      const int i = i0 + mi * 16 + r;
#pragma unroll
      for (int ni = 0; ni < 2; ++ni) {
        const int j = j0 + ni * 16;
        out[(size_t)i * 128 + j] = fmaxf(acc[mi][ni][r] + blin[j], 0.f);
      }
    }
}

extern "C" void kernel_launch(void* const* d_in, const int* in_sizes, int n_in,
                              void* d_out, int out_size, void* d_ws,
                              size_t ws_size, hipStream_t stream) {
  const float* x = (const float*)d_in[0];
  const float* Wk = (const float*)d_in[1];
  const float* Wlin = (const float*)d_in[2];
  const float* blin = (const float*)d_in[3];
  float* out = (float*)d_out;
  char* w = (char*)d_ws;
  // workspace layout (bytes):
  bf16* kmat = (bf16*)(w);                 // 4 * 4096*4096 * 2  = 134217728
  float* hpart = (float*)(w + 134217728);  // 4 * 4*4096*256*4   = 67108864
  bf16* h1T = (bf16*)(w + 201326592);      // 4 * 256*4096 * 2   = 8388608
  bf16* xhT = (bf16*)(w + 209715200);      // 2 * 256*4096 * 2   = 4194304
  bf16* U = (bf16*)(w + 213909504);        // 8192*1280 * 2      = 20971520
  bf16* WbT = (bf16*)(w + 234881024);      // 128*1280 * 2       = 327680
  float* sqv = (float*)(w + 235208704);    // 8192 * 4           = 32768
  // total ~235.2 MB

  prep<<<dim3(4096, 2), 256, 0, stream>>>(x, U, sqv);
  transk<<<dim3(64, 4, 2), 256, 0, stream>>>(x, xhT);
  wbig<<<dim3(640), 256, 0, stream>>>(Wk, Wlin, WbT);
  gemm_s<<<dim3(32, 32, 2), 256, 0, stream>>>(U, sqv, kmat);
  // pass 1: h1 = K @ x
  gemm_h<<<dim3(32, 2, 16), 256, 0, stream>>>(kmat, xhT, hpart, 1);
  reduceT<<<dim3(64, 4, 4), 256, 0, stream>>>(hpart, U, h1T, 256);
  // pass 2: h2 = K @ h1
  gemm_h<<<dim3(32, 2, 16), 256, 0, stream>>>(kmat, h1T, hpart, 0);
  reduceT<<<dim3(64, 4, 4), 256, 0, stream>>>(hpart, U, nullptr, 512);
  gemm_proj<<<dim3(64, 2), 256, 0, stream>>>(U, WbT, blin, out);
}

// Round 6
// 254.252 us; speedup vs baseline: 1.2564x; 1.0099x over previous
//
#include <hip/hip_runtime.h>
#include <hip/hip_bf16.h>

typedef __hip_bfloat16 bf16;
typedef float v4f __attribute__((ext_vector_type(4)));
typedef short v8s __attribute__((ext_vector_type(8)));

typedef const __attribute__((address_space(1))) void gvoid;
typedef __attribute__((address_space(3))) void lvoid;

__device__ __forceinline__ void async16(const void* g, void* l) {
  __builtin_amdgcn_global_load_lds((gvoid*)g, (lvoid*)l, 16, 0, 0);
}

// cardinal cubic B-spline on [0,4], 0 outside. Reference bspline(t) == b3(4t),
// wavelet(t) == b3(8t) - b3(8t-4). Clamp makes u>=4 exactly 0 (64-108+48-4).
__device__ __forceinline__ float b3(float u) {
  u = fminf(fmaxf(u, 0.f), 4.f);
  float t1 = fmaxf(u - 1.f, 0.f);
  float t2 = fmaxf(u - 2.f, 0.f);
  float t3 = fmaxf(u - 3.f, 0.f);
  float c0 = u * u * u;
  float c1 = t1 * t1 * t1;
  float c2 = t2 * t2 * t2;
  float c3 = t3 * t3 * t3;
  return (c0 - 4.f * c1 + 6.f * c2 - 4.f * c3) * (1.f / 6.f);
}

// m97-style NT GEMM mainloop: C[128 x NI*32] tile, BK elems per stage,
// bf16 MFMA 16x16x32. A: [*, lda] row-major (M rows), B: [*, ldb] row-major
// (N rows, i.e. B^T). As: 128*BK bf16, Bs: NI*32*BK bf16.
template <int NI, int BK>
__device__ __forceinline__ void mfma_loop(const bf16* __restrict__ A,
                                          const bf16* __restrict__ B, int lda,
                                          int ldb, int kLen, bf16* As, bf16* Bs,
                                          v4f acc[4][NI]) {
  const int tid = threadIdx.x;
  const int wave = tid >> 6;
  const int lane = tid & 63;
  const int quad = lane >> 4;
  const int r16 = lane & 15;
  const int wm = (wave >> 1) * 64;
  const int wn = (wave & 1) * (NI * 16);
  constexpr int CPR = BK / 8;          // 16B chunks per row
  constexpr int AQ = 128 * CPR / 256;  // async groups for A
  constexpr int BQ = NI * 32 * CPR / 256;
  char* AsC = (char*)As;
  char* BsC = (char*)Bs;
  for (int kk = 0; kk < kLen; kk += BK) {
#pragma unroll
    for (int q = 0; q < AQ; ++q) {
      const int ch = tid + 256 * q;
      const int r = ch / CPR, c = (ch % CPR) * 8;
      async16(A + (size_t)r * lda + kk + c, AsC + q * 4096 + wave * 1024);
    }
#pragma unroll
    for (int q = 0; q < BQ; ++q) {
      const int ch = tid + 256 * q;
      const int r = ch / CPR, c = (ch % CPR) * 8;
      async16(B + (size_t)r * ldb + kk + c, BsC + q * 4096 + wave * 1024);
    }
    __syncthreads();
#pragma unroll
    for (int ks = 0; ks < BK / 32; ++ks) {
      v8s af[4], bfr[NI];
#pragma unroll
      for (int mi = 0; mi < 4; ++mi)
        af[mi] =
            *(const v8s*)(As + (wm + mi * 16 + r16) * BK + ks * 32 + quad * 8);
#pragma unroll
      for (int ni = 0; ni < NI; ++ni)
        bfr[ni] =
            *(const v8s*)(Bs + (wn + ni * 16 + r16) * BK + ks * 32 + quad * 8);
#pragma unroll
      for (int mi = 0; mi < 4; ++mi)
#pragma unroll
        for (int ni = 0; ni < NI; ++ni)
          acc[mi][ni] = __builtin_amdgcn_mfma_f32_16x16x32_bf16(
              af[mi], bfr[ni], acc[mi][ni], 0, 0, 0);
    }
    __syncthreads();
  }
}

// per-row: sq-norm + bf16 cast of x into U[:, 0:256]
__global__ void prep(const float* __restrict__ x, bf16* __restrict__ U,
                     float* __restrict__ sq) {
  const int n = blockIdx.x, b = blockIdx.y, t = threadIdx.x;
  const size_t row = (size_t)b * 4096 + n;
  float v = x[row * 256 + t];
  U[row * 1280 + t] = __float2bfloat16(v);
  float s = v * v;
#pragma unroll
  for (int o = 32; o > 0; o >>= 1) s += __shfl_down(s, o, 64);
  __shared__ float ls[4];
  if ((t & 63) == 0) ls[t >> 6] = s;
  __syncthreads();
  if (t == 0) sq[row] = ls[0] + ls[1] + ls[2] + ls[3];
}

// fp32 [z][4096][256] -> bf16 [z][256][4096] (tiled transpose via LDS)
__global__ void transk(const float* __restrict__ src, bf16* __restrict__ dst) {
  __shared__ float tile[64][65];
  const int z = blockIdx.z;
  const float* s = src + (size_t)z * 4096 * 256;
  bf16* d = dst + (size_t)z * 256 * 4096;
  const int n0 = blockIdx.x * 64, d0 = blockIdx.y * 64;
  const int tx = threadIdx.x & 31, ty = threadIdx.x >> 5;
#pragma unroll
  for (int i = 0; i < 8; ++i) {
    const int r = ty + i * 8;
    const float2 v = *(const float2*)(s + (size_t)(n0 + r) * 256 + d0 + tx * 2);
    tile[r][tx * 2] = v.x;
    tile[r][tx * 2 + 1] = v.y;
  }
  __syncthreads();
#pragma unroll
  for (int i = 0; i < 8; ++i) {
    const int c = ty + i * 8;
    __hip_bfloat162 p;
    p.x = __float2bfloat16(tile[tx * 2][c]);
    p.y = __float2bfloat16(tile[tx * 2 + 1][c]);
    *(__hip_bfloat162*)(d + (size_t)(d0 + c) * 4096 + n0 + tx * 2) = p;
  }
}

// WbigT bf16 [128][1280]
__global__ void wbig(const float* __restrict__ Wk, const float* __restrict__ Wl,
                     bf16* __restrict__ WbT) {
  int idx = blockIdx.x * 256 + threadIdx.x;
  if (idx >= 128 * 1280) return;
  int j = idx / 1280, k = idx % 1280;
  int o = j & 63;
  float v = 0.f;
  if (k < 256)
    v = Wk[k * 64 + o] + Wl[k * 128 + j];
  else if (k < 512)
    v = (j < 64) ? Wk[16384 + (k - 256) * 64 + o] : 0.f;
  else if (k < 768)
    v = (j < 64) ? Wk[32768 + (k - 512) * 64 + o] : 0.f;
  else if (k < 1024)
    v = (j >= 64) ? Wk[16384 + (k - 768) * 64 + o] : 0.f;
  else
    v = (j >= 64) ? Wk[32768 + (k - 1024) * 64 + o] : 0.f;
  WbT[idx] = __float2bfloat16(v);
}

// S = x x^T tile + adjacency/spline epilogue -> bk, wk bf16 [4096][4096].
// Spline pair via 2048-entry LDS LUT over t=exp(-d2/512) in (0,1]:
// lut[i] = packed (bf16 b3(4t), bf16 b3(8t)-b3(8t-4)) at t=(i+.5)/2048.
// Bin error ~1.5e-3 ~ bf16 quantum << 2% threshold.
// Stores: lanes L,L^1 hold adjacent cols of the same rows (i is independent of
// lane bit0: quad=lane>>4) -> shfl_xor(1) + pack = dword stores, half count.
// LDS = 16K As + 16K Bs + 8K lut = 40K -> 4 blocks/CU.
__global__ __launch_bounds__(256, 4) void gemm_s(const bf16* __restrict__ U,
                                                 const float* __restrict__ sq,
                                                 bf16* __restrict__ kmat) {
  __shared__ __align__(16) bf16 As[128 * 64];
  __shared__ __align__(16) bf16 Bs[128 * 64];
  __shared__ unsigned lut[2048];
  const int tid = threadIdx.x;
  for (int i = tid; i < 2048; i += 256) {
    float t = (i + 0.5f) * (1.f / 2048.f);
    float bv = b3(4.f * t);
    float wv = b3(8.f * t) - b3(8.f * t - 4.f);
    __hip_bfloat162 p;
    p.x = __float2bfloat16(bv);  // low 16 = b-kernel
    p.y = __float2bfloat16(wv);  // high 16 = wavelet
    lut[i] = *(unsigned*)&p;
  }
  const int z = blockIdx.z;
  const bf16* A = U + (size_t)z * 4096 * 1280 + (size_t)blockIdx.x * 128 * 1280;
  const bf16* B = U + (size_t)z * 4096 * 1280 + (size_t)blockIdx.y * 128 * 1280;
  v4f acc[4][4];
#pragma unroll
  for (int a = 0; a < 4; ++a)
#pragma unroll
    for (int b2 = 0; b2 < 4; ++b2) acc[a][b2] = (v4f){0.f, 0.f, 0.f, 0.f};
  mfma_loop<4, 64>(A, B, 1280, 1280, 256, As, Bs, acc);
  const int wave = tid >> 6, lane = tid & 63;
  const int quad = lane >> 4, r16 = lane & 15;
  const int wm = (wave >> 1) * 64, wn = (wave & 1) * 64;
  const float* sqr = sq + (size_t)z * 4096;
  unsigned short* bk = (unsigned short*)(kmat + (size_t)(z * 2) * 4096 * 4096);
  unsigned short* wk = bk + (size_t)4096 * 4096;
  const int i0 = blockIdx.x * 128 + wm + quad * 4;
  const int j0 = blockIdx.y * 128 + wn + r16;
  const int par = lane & 1;       // 0: handles rows r=0,1 ; 1: rows r=2,3
  const int jc = j0 - par;        // even column of this lane's pair
  float sqj[4];
#pragma unroll
  for (int ni = 0; ni < 4; ++ni) sqj[ni] = sqr[j0 + ni * 16];
  const float c = -1.4426950408889634f / 512.f;  // -log2(e)/512
  float si[16];
#pragma unroll
  for (int mi = 0; mi < 4; ++mi)
#pragma unroll
    for (int r = 0; r < 4; ++r) si[mi * 4 + r] = sqr[i0 + mi * 16 + r];
#pragma unroll
  for (int mi = 0; mi < 4; ++mi) {
#pragma unroll
    for (int ni = 0; ni < 4; ++ni) {
      unsigned pv[4];
#pragma unroll
      for (int r = 0; r < 4; ++r) {
        float s = acc[mi][ni][r];
        float d2 = fmaxf(si[mi * 4 + r] + sqj[ni] - 2.f * s, 0.f);
        float t = __builtin_amdgcn_exp2f(d2 * c);
        int idx = (int)fminf(t * 2048.f, 2047.f);
        pv[r] = lut[idx];
      }
      unsigned ov[4];
#pragma unroll
      for (int r = 0; r < 4; ++r) ov[r] = __shfl_xor((int)pv[r], 1, 64);
#pragma unroll
      for (int rr = 0; rr < 2; ++rr) {
        const int r = par * 2 + rr;
        const unsigned a = pv[r], b2 = ov[r];
        const unsigned lo = par ? b2 : a;   // left (even) column
        const unsigned hi = par ? a : b2;   // right (odd) column
        const unsigned bkd = (lo & 0xffffu) | (hi << 16);
        const unsigned wkd = (lo >> 16) | (hi & 0xffff0000u);
        const int i = i0 + mi * 16 + r;
        const size_t off = (size_t)i * 4096 + jc + ni * 16;
        *(unsigned*)(bk + off) = bkd;
        *(unsigned*)(wk + off) = wkd;
      }
    }
  }
}

// h-partial = K[:, split] @ H[split, :] : split-K x4, BK=64, 128x128 tile.
// A = kernel matrix [4096][4096] bf16, Bt = H^T bf16 [256][4096].
// writes fp32 partial to hpart[split][z][4096][256].
__global__ __launch_bounds__(256, 4) void gemm_h(const bf16* __restrict__ kmat,
                                                 const bf16* __restrict__ BtBase,
                                                 float* __restrict__ hpart,
                                                 int btShift) {
  __shared__ __align__(16) bf16 As[128 * 64];
  __shared__ __align__(16) bf16 Bs[128 * 64];
  const int bz = blockIdx.z;
  const int z = bz >> 2, split = bz & 3;
  const int kk0 = split * 1024;
  const bf16* A =
      kmat + (size_t)z * 4096 * 4096 + (size_t)blockIdx.x * 128 * 4096 + kk0;
  const bf16* B = BtBase + (size_t)(z >> btShift) * 256 * 4096 +
                  (size_t)blockIdx.y * 128 * 4096 + kk0;
  v4f acc[4][4];
#pragma unroll
  for (int a = 0; a < 4; ++a)
#pragma unroll
    for (int b2 = 0; b2 < 4; ++b2) acc[a][b2] = (v4f){0.f, 0.f, 0.f, 0.f};
  mfma_loop<4, 64>(A, B, 4096, 4096, 1024, As, Bs, acc);
  const int tid = threadIdx.x, wave = tid >> 6, lane = tid & 63;
  const int quad = lane >> 4, r16 = lane & 15;
  const int wm = (wave >> 1) * 64, wn = (wave & 1) * 64;
  float* H = hpart + ((size_t)split * 4 + z) * 4096 * 256;
  const int i0 = blockIdx.x * 128 + wm + quad * 4;
  const int j0 = blockIdx.y * 128 + wn + r16;
#pragma unroll
  for (int mi = 0; mi < 4; ++mi)
#pragma unroll
    for (int r = 0; r < 4; ++r) {
      const int i = i0 + mi * 16 + r;
#pragma unroll
      for (int ni = 0; ni < 4; ++ni)
        H[(size_t)i * 256 + j0 + ni * 16] = acc[mi][ni][r];
    }
}

// sum the four split-K partials; write bf16 slice into U[:, uoff..] and
// (pass 1 only) transposed bf16 into hT [z][256][4096].
__global__ void reduceT(const float* __restrict__ hpart, bf16* __restrict__ U,
                        bf16* __restrict__ hT, int uoffBase) {
  __shared__ float tile[64][65];
  const int z = blockIdx.z;
  const int b = z >> 1, kern = z & 1;
  const int uoff = uoffBase + kern * 512;
  const int n0 = blockIdx.x * 64, d0 = blockIdx.y * 64;
  const int tx = threadIdx.x & 31, ty = threadIdx.x >> 5;
  const size_t sstride = (size_t)4 * 4096 * 256;
  const float* s0 = hpart + (size_t)z * 4096 * 256;
#pragma unroll
  for (int i = 0; i < 8; ++i) {
    const int r = ty + i * 8;
    const size_t off = (size_t)(n0 + r) * 256 + d0 + tx * 2;
    float vx = 0.f, vy = 0.f;
#pragma unroll
    for (int k = 0; k < 4; ++k) {
      const float2 a = *(const float2*)(s0 + k * sstride + off);
      vx += a.x;
      vy += a.y;
    }
    tile[r][tx * 2] = vx;
    tile[r][tx * 2 + 1] = vy;
    __hip_bfloat162 p;
    p.x = __float2bfloat16(vx);
    p.y = __float2bfloat16(vy);
    *(__hip_bfloat162*)(U + (size_t)(b * 4096 + n0 + r) * 1280 + uoff + d0 +
                        tx * 2) = p;
  }
  if (hT) {
    __syncthreads();
#pragma unroll
    for (int i = 0; i < 8; ++i) {
      const int c = ty + i * 8;
      __hip_bfloat162 p;
      p.x = __float2bfloat16(tile[tx * 2][c]);
      p.y = __float2bfloat16(tile[tx * 2 + 1][c]);
      *(__hip_bfloat162*)(hT + (size_t)z * 256 * 4096 + (size_t)(d0 + c) * 4096 +
                          n0 + tx * 2) = p;
    }
  }
}

// out = relu(U @ Wbig + b_lin), M=8192, K=1280, N=128
__global__ __launch_bounds__(256, 4) void gemm_proj(
    const bf16* __restrict__ U, const bf16* __restrict__ WbT,
    const float* __restrict__ blin, float* __restrict__ out) {
  __shared__ __align__(16) bf16 As[128 * 64];
  __shared__ __align__(16) bf16 Bs[64 * 64];
  const bf16* A = U + (size_t)blockIdx.x * 128 * 1280;
  const bf16* B = WbT + (size_t)blockIdx.y * 64 * 1280;
  v4f acc[4][2];
#pragma unroll
  for (int a = 0; a < 4; ++a)
#pragma unroll
    for (int b2 = 0; b2 < 2; ++b2) acc[a][b2] = (v4f){0.f, 0.f, 0.f, 0.f};
  mfma_loop<2, 64>(A, B, 1280, 1280, 1280, As, Bs, acc);
  const int tid = threadIdx.x, wave = tid >> 6, lane = tid & 63;
  const int quad = lane >> 4, r16 = lane & 15;
  const int wm = (wave >> 1) * 64, wn = (wave & 1) * 32;
  const int i0 = blockIdx.x * 128 + wm + quad * 4;
  const int j0 = blockIdx.y * 64 + wn + r16;
#pragma unroll
  for (int mi = 0; mi < 4; ++mi)
#pragma unroll
    for (int r = 0; r < 4; ++r) {
      const int i = i0 + mi * 16 + r;
#pragma unroll
      for (int ni = 0; ni < 2; ++ni) {
        const int j = j0 + ni * 16;
        out[(size_t)i * 128 + j] = fmaxf(acc[mi][ni][r] + blin[j], 0.f);
      }
    }
}

extern "C" void kernel_launch(void* const* d_in, const int* in_sizes, int n_in,
                              void* d_out, int out_size, void* d_ws,
                              size_t ws_size, hipStream_t stream) {
  const float* x = (const float*)d_in[0];
  const float* Wk = (const float*)d_in[1];
  const float* Wlin = (const float*)d_in[2];
  const float* blin = (const float*)d_in[3];
  float* out = (float*)d_out;
  char* w = (char*)d_ws;
  // workspace layout (bytes):
  bf16* kmat = (bf16*)(w);                 // 4 * 4096*4096 * 2  = 134217728
  float* hpart = (float*)(w + 134217728);  // 4 * 4*4096*256*4   = 67108864
  bf16* h1T = (bf16*)(w + 201326592);      // 4 * 256*4096 * 2   = 8388608
  bf16* xhT = (bf16*)(w + 209715200);      // 2 * 256*4096 * 2   = 4194304
  bf16* U = (bf16*)(w + 213909504);        // 8192*1280 * 2      = 20971520
  bf16* WbT = (bf16*)(w + 234881024);      // 128*1280 * 2       = 327680
  float* sqv = (float*)(w + 235208704);    // 8192 * 4           = 32768
  // total ~235.2 MB

  prep<<<dim3(4096, 2), 256, 0, stream>>>(x, U, sqv);
  transk<<<dim3(64, 4, 2), 256, 0, stream>>>(x, xhT);
  wbig<<<dim3(640), 256, 0, stream>>>(Wk, Wlin, WbT);
  gemm_s<<<dim3(32, 32, 2), 256, 0, stream>>>(U, sqv, kmat);
  // pass 1: h1 = K @ x
  gemm_h<<<dim3(32, 2, 16), 256, 0, stream>>>(kmat, xhT, hpart, 1);
  reduceT<<<dim3(64, 4, 4), 256, 0, stream>>>(hpart, U, h1T, 256);
  // pass 2: h2 = K @ h1
  gemm_h<<<dim3(32, 2, 16), 256, 0, stream>>>(kmat, h1T, hpart, 0);
  reduceT<<<dim3(64, 4, 4), 256, 0, stream>>>(hpart, U, nullptr, 512);
  gemm_proj<<<dim3(64, 2), 256, 0, stream>>>(U, WbT, blin, out);
}